// Round 13
// baseline (1262.790 us; speedup 1.0000x reference)
//
#include <hip/hip_runtime.h>

// KG attention, 3 hops.  (round-10 k_qproj + persistent k_fused with cross-window prefetch)
//  - softmax denom & cnt cancel under L2 normalize: agg_next = normalize(sum_e exp(att-m)*X_e)
//  - agg in bf16 between hops; eemb pre-converted to bf16
//  - CSR by head; nodes partitioned into blocks by row_off[n]/96 -> window <= 128 edges
//  - k_fused: persistent blocks, window i+1's agg-gathers issued & reg-held during window i's
//    MFMA+epilogue (T14 async-stage) -> gather latency hidden for 5/6 windows
// Workspace ~113 MB.

#define DD 128
#define CAP1 96

typedef unsigned short u16;
typedef unsigned int u32;
typedef __attribute__((ext_vector_type(8))) __bf16 bf16x8;
typedef __attribute__((ext_vector_type(4))) float f32x4;

__device__ __forceinline__ float bf2f(u16 u) { return __uint_as_float(((u32)u) << 16); }
__device__ __forceinline__ u16 f2bf(float f) {
    u32 u = __float_as_uint(f);
    u += 0x7FFFu + ((u >> 16) & 1u);   // RNE
    return (u16)(u >> 16);
}
__device__ __forceinline__ u32 cvt_pk_bf16(float a, float b) {
    u32 r;
    asm("v_cvt_pk_bf16_f32 %0, %1, %2" : "=v"(r) : "v"(a), "v"(b));
    return r;
}
// elementwise product of two bf16 pairs -> bf16 pair
__device__ __forceinline__ u32 mul_bf_bf(u32 a2, u32 b2) {
    float lo = bf2f((u16)(a2 & 0xffffu)) * bf2f((u16)(b2 & 0xffffu));
    float hi = bf2f((u16)(a2 >> 16)) * bf2f((u16)(b2 >> 16));
    return cvt_pk_bf16(lo, hi);
}
__device__ __forceinline__ float fast_tanh(float x) {
    float e = __builtin_amdgcn_exp2f(x * 2.8853900817779268f);  // e^{2x}
    float r = __builtin_amdgcn_rcpf(e + 1.f);
    return __builtin_fmaf(-2.f, r, 1.f);
}

// ------------------- f32 -> bf16 pack (entity seed, eemb) -------------------------------
__global__ void k_cvt(const float* __restrict__ src, u16* __restrict__ dst, int n8) {
    int i = blockIdx.x * blockDim.x + threadIdx.x;
    if (i >= n8) return;
    float4 a = ((const float4*)src)[i * 2];
    float4 b = ((const float4*)src)[i * 2 + 1];
    u32 pk[4] = {cvt_pk_bf16(a.x, a.y), cvt_pk_bf16(a.z, a.w),
                 cvt_pk_bf16(b.x, b.y), cvt_pk_bf16(b.z, b.w)};
    ((uint4*)dst)[i] = *(uint4*)pk;
}

// ------------------- CSR build (once per call; head is hop-invariant) -------------------
__global__ void k_hist(const int* __restrict__ head, int E, int* __restrict__ counts) {
    int e = blockIdx.x * blockDim.x + threadIdx.x;
    if (e < E) atomicAdd(&counts[head[e]], 1);
}

__global__ void k_scan_a(const int* __restrict__ counts, int N, int* __restrict__ row_off,
                         int* __restrict__ partials) {
    __shared__ int sw[16];
    int i = blockIdx.x * 1024 + threadIdx.x;
    int v = (i < N) ? counts[i] : 0;
    int lane = threadIdx.x & 63, wid = threadIdx.x >> 6;
    int x = v;
    #pragma unroll
    for (int off = 1; off < 64; off <<= 1) {
        int t = __shfl_up(x, off);
        if (lane >= off) x += t;
    }
    if (lane == 63) sw[wid] = x;
    __syncthreads();
    if (threadIdx.x == 0) {
        int run = 0;
        for (int w0 = 0; w0 < 16; w0++) { int t = sw[w0]; sw[w0] = run; run += t; }
        partials[blockIdx.x] = run;
    }
    __syncthreads();
    if (i < N) row_off[i] = x - v + sw[wid];   // chunk-local exclusive
}
__global__ void k_scan_b(int* __restrict__ partials, int nch) {
    if (blockIdx.x == 0 && threadIdx.x == 0) {
        int run = 0;
        for (int c = 0; c < nch; c++) { int t = partials[c]; partials[c] = run; run += t; }
    }
}
__global__ void k_scan_c(int* __restrict__ row_off, const int* __restrict__ partials, int N, int E) {
    int i = blockIdx.x * 1024 + threadIdx.x;
    if (i < N) row_off[i] += partials[blockIdx.x];
    if (i == 0) row_off[N] = E;
}
__global__ void k_fill(const int* __restrict__ head, const int* __restrict__ tail,
                       const int* __restrict__ etype, int E, const int* __restrict__ row_off,
                       int* __restrict__ cursor, int* __restrict__ c_head,
                       int* __restrict__ c_tail, int* __restrict__ c_type) {
    int e = blockIdx.x * blockDim.x + threadIdx.x;
    if (e >= E) return;
    int h = head[e];
    int p = row_off[h] + atomicAdd(&cursor[h], 1);
    c_head[p] = h; c_tail[p] = tail[e]; c_type[p] = etype[e];
}

// node -> owning block (floor(start/CAP1)); block covers whole nodes, tile <= 128 edges
__global__ void k_blk(const int* __restrict__ row_off, int N,
                      int* __restrict__ blk_n0, int* __restrict__ blk_n1) {
    int n = blockIdx.x * blockDim.x + threadIdx.x;
    if (n >= N) return;
    int b = row_off[n] / CAP1;
    atomicMin(&blk_n0[b], n);
    atomicMax(&blk_n1[b], n + 1);
}
// pack per-block meta: {n0, n1, p0, span}
__global__ void k_meta(const int* __restrict__ blk_n0, const int* __restrict__ blk_n1,
                       const int* __restrict__ row_off, int NB, int4* __restrict__ meta) {
    int b = blockIdx.x * blockDim.x + threadIdx.x;
    if (b >= NB) return;
    int n0 = blk_n0[b];
    if (n0 == 0x7f7f7f7f) { meta[b] = make_int4(-1, 0, 0, 0); return; }
    int n1 = blk_n1[b];
    int p0 = row_off[n0];
    int span = row_off[n1] - p0;
    if (span > 128) span = 128;
    meta[b] = make_int4(n0, n1, p0, span);
}

// ------------------- weight prep -------------------------------------------------------
// swizzled transposed image (for LDS-linear copy + swizzled ds_read in k_qproj)
__global__ void k_prep_swz(const float* __restrict__ src, u16* __restrict__ dst_swz) {
    int idx = blockIdx.x * 256 + threadIdx.x;
    if (idx >= DD * DD) return;
    int n = idx >> 7, k = idx & 127;
    float v = src[k * DD + n];
    int byte = (n * 256 + k * 2) ^ ((n & 7) << 4);
    dst_swz[byte >> 1] = f2bf(v);
}
// plain transposed image (for direct global B-fragment reads in k_fused)
__global__ void k_prep_plain(const float* __restrict__ src, u16* __restrict__ dst) {
    int idx = blockIdx.x * 256 + threadIdx.x;
    if (idx >= DD * DD) return;
    int n = idx >> 7, k = idx & 127;
    dst[n * DD + k] = f2bf(src[k * DD + n]);
}

// ------------------- qh = aggb @ q_w  (bf16 out) via MFMA (round-10 proven) -------------
__global__ void __launch_bounds__(256) k_qproj(const u16* __restrict__ aggb,
                                               const uint4* __restrict__ qwT_swz,
                                               u16* __restrict__ qh, int N) {
    __shared__ u16 sA[DD * DD];    // 32 KB, swizzled bf16 rows
    __shared__ u16 sB[DD * DD];    // 32 KB, qwT swizzled
    int tid = threadIdx.x;
    {
        uint4* dst = (uint4*)sB;
        #pragma unroll
        for (int i = 0; i < 8; ++i) dst[i * 256 + tid] = qwT_swz[i * 256 + tid];
    }
    long base = (long)blockIdx.x * 128;
    int qq = tid & 3, er = tid >> 2;
    #pragma unroll
    for (int pass = 0; pass < 2; ++pass) {
        int rloc = pass * 64 + er;
        long n = base + rloc;
        int d0 = qq * 32;
        __align__(16) uint4 pk[4];
        if (n < N) {
            const uint4* ar = (const uint4*)(aggb + (size_t)n * DD + d0);
            #pragma unroll
            for (int c = 0; c < 4; ++c) pk[c] = ar[c];
        } else {
            #pragma unroll
            for (int c = 0; c < 4; ++c) pk[c] = (uint4){0u, 0u, 0u, 0u};
        }
        char* basep = (char*)sA;
        #pragma unroll
        for (int c = 0; c < 4; ++c) {
            int byte = (rloc * 256 + d0 * 2 + c * 16) ^ ((rloc & 7) << 4);
            *(uint4*)(basep + byte) = pk[c];
        }
    }
    __syncthreads();
    int lane = tid & 63, wid = tid >> 6;
    int lr = lane & 15, lg = lane >> 4;
    int rgbase = wid * 32;
    f32x4 acc[2][8];
    #pragma unroll
    for (int g = 0; g < 2; ++g)
        #pragma unroll
        for (int t = 0; t < 8; ++t) acc[g][t] = (f32x4){0.f, 0.f, 0.f, 0.f};
    const char* ab_ = (const char*)sA;
    const char* bb_ = (const char*)sB;
    int sw = (lr & 7) << 4;
    #pragma unroll
    for (int kc = 0; kc < 4; ++kc) {
        int koffb = kc * 64 + lg * 16;
        int r0 = rgbase + lr;
        bf16x8 a0 = *(const bf16x8*)(ab_ + ((r0 * 256 + koffb) ^ sw));
        bf16x8 a1 = *(const bf16x8*)(ab_ + (((r0 + 16) * 256 + koffb) ^ sw));
        #pragma unroll
        for (int t = 0; t < 8; ++t) {
            int n = t * 16 + lr;
            bf16x8 b = *(const bf16x8*)(bb_ + ((n * 256 + koffb) ^ sw));
            acc[0][t] = __builtin_amdgcn_mfma_f32_16x16x32_bf16(a0, b, acc[0][t], 0, 0, 0);
            acc[1][t] = __builtin_amdgcn_mfma_f32_16x16x32_bf16(a1, b, acc[1][t], 0, 0, 0);
        }
    }
    #pragma unroll
    for (int g = 0; g < 2; ++g)
        #pragma unroll
        for (int r = 0; r < 4; ++r) {
            long row = base + rgbase + g * 16 + lg * 4 + r;
            if (row < N) {
                u16* qrow = qh + (size_t)row * DD + lr;
                #pragma unroll
                for (int t = 0; t < 8; ++t) qrow[t * 16] = f2bf(acc[g][t][r]);
            }
        }
}

// ------------------- fused: persistent blocks + cross-window prefetch -------------------
__global__ void __launch_bounds__(256, 4) k_fused(
        const u16* __restrict__ aggb, const u16* __restrict__ eembb,
        const u16* __restrict__ kwT, const u16* __restrict__ qh,
        const int* __restrict__ c_head, const int* __restrict__ c_tail,
        const int* __restrict__ c_type, const int* __restrict__ row_off,
        const int4* __restrict__ meta, const float* __restrict__ entity,
        u16* __restrict__ aggb_next, float* __restrict__ outacc,
        int mode, int NB, int E) {
    __shared__ u16 sX[DD * DD];    // 32 KB, swizzled bf16 X rows
    __shared__ float satt[128];
    int tid = threadIdx.x;
    int qq = tid & 3, er = tid >> 2;       // 4 threads/edge, 32 dims each
    int d0 = qq * 32;
    int lane = tid & 63, wid = tid >> 6;
    int lr = lane & 15, lg = lane >> 4;
    int sw = (lr & 7) << 4;

    int b = blockIdx.x;
    if (b >= NB) return;
    int4 mt = meta[b];
    uint4 av0[4], av1[4];
    int rl0 = 0, rl1 = 0;
    bool v0 = false, v1 = false;
    {   // initial prefetch for window b
        int p0 = mt.z, span = mt.w;
        v0 = (mt.x >= 0) && (er < span);
        v1 = (mt.x >= 0) && (64 + er < span);
        int pp0 = min(v0 ? p0 + er : p0, E - 1);
        int pp1 = min(v1 ? p0 + 64 + er : p0, E - 1);
        int t0 = c_tail[pp0], t1 = c_tail[pp1];
        rl0 = c_type[pp0]; rl1 = c_type[pp1];
        const uint4* ar0 = (const uint4*)(aggb + (size_t)t0 * DD + d0);
        const uint4* ar1 = (const uint4*)(aggb + (size_t)t1 * DD + d0);
        #pragma unroll
        for (int c = 0; c < 4; ++c) { av0[c] = ar0[c]; av1[c] = ar1[c]; }
    }
    for (;;) {
        // ---- write prefetched X = aggb[tail] (*) eembb[type] to LDS (swizzled) ----
        if (mt.x >= 0) {
            const uint4* rr0 = (const uint4*)(eembb + (size_t)rl0 * DD + d0);
            const uint4* rr1 = (const uint4*)(eembb + (size_t)rl1 * DD + d0);
            char* base = (char*)sX;
            #pragma unroll
            for (int c = 0; c < 4; ++c) {
                uint4 rv = rr0[c];
                __align__(16) u32 pk[4];
                if (v0) {
                    pk[0] = mul_bf_bf(av0[c].x, rv.x);
                    pk[1] = mul_bf_bf(av0[c].y, rv.y);
                    pk[2] = mul_bf_bf(av0[c].z, rv.z);
                    pk[3] = mul_bf_bf(av0[c].w, rv.w);
                } else { pk[0] = pk[1] = pk[2] = pk[3] = 0u; }
                int byte = (er * 256 + d0 * 2 + c * 16) ^ ((er & 7) << 4);
                *(uint4*)(base + byte) = *(const uint4*)pk;
            }
            int e1 = 64 + er;
            #pragma unroll
            for (int c = 0; c < 4; ++c) {
                uint4 rv = rr1[c];
                __align__(16) u32 pk[4];
                if (v1) {
                    pk[0] = mul_bf_bf(av1[c].x, rv.x);
                    pk[1] = mul_bf_bf(av1[c].y, rv.y);
                    pk[2] = mul_bf_bf(av1[c].z, rv.z);
                    pk[3] = mul_bf_bf(av1[c].w, rv.w);
                } else { pk[0] = pk[1] = pk[2] = pk[3] = 0u; }
                int byte = (e1 * 256 + d0 * 2 + c * 16) ^ ((e1 & 7) << 4);
                *(uint4*)(base + byte) = *(const uint4*)pk;
            }
        }
        __syncthreads();
        // ---- issue next window's prefetch (loads stay in flight during compute) ----
        int bn = b + gridDim.x;
        bool have_next = (bn < NB);
        int4 mtn = make_int4(-1, 0, 0, 0);
        uint4 nav0[4], nav1[4];
        int nrl0 = 0, nrl1 = 0;
        bool nv0 = false, nv1 = false;
        if (have_next) {
            mtn = meta[bn];
            int p0 = mtn.z, span = mtn.w;
            nv0 = (mtn.x >= 0) && (er < span);
            nv1 = (mtn.x >= 0) && (64 + er < span);
            int pp0 = min(nv0 ? p0 + er : p0, E - 1);
            int pp1 = min(nv1 ? p0 + 64 + er : p0, E - 1);
            int t0 = c_tail[pp0], t1 = c_tail[pp1];
            nrl0 = c_type[pp0]; nrl1 = c_type[pp1];
            const uint4* ar0 = (const uint4*)(aggb + (size_t)t0 * DD + d0);
            const uint4* ar1 = (const uint4*)(aggb + (size_t)t1 * DD + d0);
            #pragma unroll
            for (int c = 0; c < 4; ++c) { nav0[c] = ar0[c]; nav1[c] = ar1[c]; }
        }
        // ---- compute current window ----
        if (mt.x >= 0) {
            int n0 = mt.x, n1 = mt.y, p0 = mt.z, span = mt.w;
            const char* xb_ = (const char*)sX;
            int egbase = wid * 32;
            bf16x8 afrag[2][4];
            #pragma unroll
            for (int kc = 0; kc < 4; ++kc) {
                int koffb = kc * 64 + lg * 16;
                int r0 = egbase + lr;
                afrag[0][kc] = *(const bf16x8*)(xb_ + ((r0 * 256 + koffb) ^ sw));
                afrag[1][kc] = *(const bf16x8*)(xb_ + (((r0 + 16) * 256 + koffb) ^ sw));
            }
            int hh[8];
            #pragma unroll
            for (int g = 0; g < 2; ++g)
                #pragma unroll
                for (int r = 0; r < 4; ++r) {
                    int eloc = egbase + g * 16 + lg * 4 + r;
                    hh[g * 4 + r] = (eloc < span) ? c_head[p0 + eloc] : 0;
                }
            float attv[8] = {0.f, 0.f, 0.f, 0.f, 0.f, 0.f, 0.f, 0.f};
            #pragma unroll
            for (int t = 0; t < 8; ++t) {
                f32x4 acc0 = (f32x4){0.f, 0.f, 0.f, 0.f};
                f32x4 acc1 = (f32x4){0.f, 0.f, 0.f, 0.f};
                int n = t * 16 + lr;
                #pragma unroll
                for (int kc = 0; kc < 4; ++kc) {
                    int koffe = kc * 32 + lg * 8;
                    bf16x8 bb = *(const bf16x8*)(kwT + n * DD + koffe);
                    acc0 = __builtin_amdgcn_mfma_f32_16x16x32_bf16(afrag[0][kc], bb, acc0, 0, 0, 0);
                    acc1 = __builtin_amdgcn_mfma_f32_16x16x32_bf16(afrag[1][kc], bb, acc1, 0, 0, 0);
                }
                // C/D: col = lane&15, row = (lane>>4)*4 + reg
                #pragma unroll
                for (int r = 0; r < 4; ++r) {
                    attv[r]     += fast_tanh(acc0[r]) * bf2f(qh[(size_t)hh[r] * DD + t * 16 + lr]);
                    attv[4 + r] += fast_tanh(acc1[r]) * bf2f(qh[(size_t)hh[4 + r] * DD + t * 16 + lr]);
                }
            }
            #pragma unroll
            for (int off = 1; off < 16; off <<= 1) {
                #pragma unroll
                for (int i = 0; i < 8; ++i) attv[i] += __shfl_xor(attv[i], off);
            }
            if (lr == 0) {
                #pragma unroll
                for (int g = 0; g < 2; ++g)
                    #pragma unroll
                    for (int r = 0; r < 4; ++r) {
                        int eloc = egbase + g * 16 + lg * 4 + r;
                        if (eloc < span) satt[eloc] = attv[g * 4 + r];
                    }
            }
            __syncthreads();
            // per-node: lane-parallel exact max, weighted sum from LDS X, normalize, out
            for (int n = n0 + wid; n < n1; n += 4) {
                int s0 = row_off[n] - p0;
                int s1 = min(row_off[n + 1] - p0, 128);
                float a0 = 0.f, a1 = 0.f;
                if (s1 > s0) {
                    float mv = -1e30f;
                    int pp = s0 + lane;
                    if (pp < s1) mv = satt[pp];
                    if (pp + 64 < s1) mv = fmaxf(mv, satt[pp + 64]);
                    #pragma unroll
                    for (int off = 1; off < 64; off <<= 1) mv = fmaxf(mv, __shfl_xor(mv, off));
                    #pragma unroll 2
                    for (int p = s0; p < s1; ++p) {
                        float wgt = __expf(satt[p] - mv);
                        int byte = (p * 256 + lane * 4) ^ ((p & 7) << 4);
                        u32 xv = *(const u32*)((const char*)sX + byte);
                        a0 += wgt * bf2f((u16)(xv & 0xffffu));
                        a1 += wgt * bf2f((u16)(xv >> 16));
                    }
                    float s = a0 * a0 + a1 * a1;
                    #pragma unroll
                    for (int off = 1; off < 64; off <<= 1) s += __shfl_xor(s, off);
                    float sc = 1.f / fmaxf(sqrtf(s), 1e-12f);
                    a0 *= sc; a1 *= sc;
                }
                size_t idx = (size_t)n * DD + lane * 2;
                *(u32*)(aggb_next + idx) = cvt_pk_bf16(a0, a1);
                float o0, o1;
                if (mode == 0) { o0 = a0; o1 = a1; }
                else { o0 = outacc[idx] + a0; o1 = outacc[idx + 1] + a1; }
                if (mode == 2) { o0 += 3.f * entity[idx]; o1 += 3.f * entity[idx + 1]; }
                outacc[idx] = o0; outacc[idx + 1] = o1;
            }
        }
        __syncthreads();   // all reads of sX/satt complete before next write
        if (!have_next) break;
        b = bn; mt = mtn;
        #pragma unroll
        for (int c = 0; c < 4; ++c) { av0[c] = nav0[c]; av1[c] = nav1[c]; }
        rl0 = nrl0; rl1 = nrl1; v0 = nv0; v1 = nv1;
    }
}

extern "C" void kernel_launch(void* const* d_in, const int* in_sizes, int n_in,
                              void* d_out, int out_size, void* d_ws, size_t ws_size,
                              hipStream_t stream) {
    const float* entity = (const float*)d_in[0];
    const float* eemb   = (const float*)d_in[1];
    const float* qw     = (const float*)d_in[2];
    const float* kw     = (const float*)d_in[3];
    const int*   eidx   = (const int*)d_in[4];
    const int*   etype  = (const int*)d_in[5];
    const int N = in_sizes[0] / DD;
    const int E = in_sizes[5];
    const int NREL = in_sizes[1] / DD;
    const int* head = eidx;
    const int* tail = eidx + E;
    const int NB = E / CAP1 + 2;

    // workspace carve (~113 MB)
    char* w = (char*)d_ws;
    auto carve = [&](size_t bytes) -> void* {
        void* p = (void*)w;
        w += ((bytes + 255) / 256) * 256;
        return p;
    };
    u16* aggbA     = (u16*)carve((size_t)N * DD * 2);
    u16* aggbB     = (u16*)carve((size_t)N * DD * 2);
    u16* aggb0     = (u16*)carve((size_t)N * DD * 2);
    u16* qh        = (u16*)carve((size_t)N * DD * 2);
    u16* eembb     = (u16*)carve((size_t)NREL * DD * 2);
    int* counts    = (int*)carve((size_t)N * 4);
    int* row_off   = (int*)carve((size_t)(N + 1) * 4);
    int* cursor    = (int*)carve((size_t)N * 4);
    int* c_head    = (int*)carve((size_t)E * 4);
    int* c_tail    = (int*)carve((size_t)E * 4);
    int* c_type    = (int*)carve((size_t)E * 4);
    u16* qwT_swz   = (u16*)carve((size_t)DD * DD * 2);
    u16* kwT       = (u16*)carve((size_t)DD * DD * 2);
    int* blk_n0    = (int*)carve((size_t)NB * 4);
    int* blk_n1    = (int*)carve((size_t)NB * 4);
    int4* meta     = (int4*)carve((size_t)NB * 16);
    int* partials  = (int*)carve(4096);
    (void)ws_size; (void)n_in; (void)out_size;

    hipMemsetAsync(counts, 0, (size_t)N * 4, stream);
    hipMemsetAsync(cursor, 0, (size_t)N * 4, stream);
    hipMemsetAsync(blk_n0, 0x7f, (size_t)NB * 4, stream);
    hipMemsetAsync(blk_n1, 0, (size_t)NB * 4, stream);
    k_prep_swz<<<(DD * DD + 255) / 256, 256, 0, stream>>>(qw, qwT_swz);
    k_prep_plain<<<(DD * DD + 255) / 256, 256, 0, stream>>>(kw, kwT);
    int n8 = N * DD / 8;
    k_cvt<<<(n8 + 255) / 256, 256, 0, stream>>>(entity, aggb0, n8);
    int r8 = NREL * DD / 8;
    k_cvt<<<(r8 + 255) / 256, 256, 0, stream>>>(eemb, eembb, r8);
    k_hist<<<(E + 255) / 256, 256, 0, stream>>>(head, E, counts);
    int nch = (N + 1023) / 1024;
    k_scan_a<<<nch, 1024, 0, stream>>>(counts, N, row_off, partials);
    k_scan_b<<<1, 64, 0, stream>>>(partials, nch);
    k_scan_c<<<nch, 1024, 0, stream>>>(row_off, partials, N, E);
    k_fill<<<(E + 255) / 256, 256, 0, stream>>>(head, tail, etype, E, row_off, cursor,
                                                c_head, c_tail, c_type);
    k_blk<<<(N + 255) / 256, 256, 0, stream>>>(row_off, N, blk_n0, blk_n1);
    k_meta<<<(NB + 255) / 256, 256, 0, stream>>>(blk_n0, blk_n1, row_off, NB, meta);

    int grid = NB < 1024 ? NB : 1024;
    const u16* cur = aggb0;
    u16* bufs[2] = {aggbA, aggbB};
    for (int hop = 0; hop < 3; hop++) {
        k_qproj<<<(N + 127) / 128, 256, 0, stream>>>(cur, (const uint4*)qwT_swz, qh, N);
        u16* nxt = bufs[hop & 1];
        int mode = (hop == 0) ? 0 : ((hop == 2) ? 2 : 1);
        k_fused<<<grid, 256, 0, stream>>>(cur, eembb, kwT, qh, c_head, c_tail, c_type,
                                          row_off, meta, entity,
                                          nxt, (float*)d_out, mode, NB, E);
        cur = nxt;
    }
}

// Round 14
// 637.338 us; speedup vs baseline: 1.9814x; 1.9814x over previous
//
#include <hip/hip_runtime.h>

// KG attention, 3 hops.  (best-known composition: r12 k_fused + r10 k_qproj)
//  - softmax denom & cnt cancel under L2 normalize: agg_next = normalize(sum_e exp(att-m)*X_e)
//  - agg in bf16 between hops; eemb pre-converted to bf16
//  - CSR by head; nodes partitioned into blocks by row_off[n]/96 -> window <= 128 edges
//  - k_fused (256 thr, 4 waves): batched gather stage -> S=X@kwT MFMA -> att in LDS ->
//    lane-parallel segment max -> weighted sum from LDS X -> normalize -> out
//  - k_qproj: A + qwT both staged in LDS (proven fastest variant)
// Workspace ~113 MB.

#define DD 128
#define CAP1 96

typedef unsigned short u16;
typedef unsigned int u32;
typedef __attribute__((ext_vector_type(8))) __bf16 bf16x8;
typedef __attribute__((ext_vector_type(4))) float f32x4;

__device__ __forceinline__ float bf2f(u16 u) { return __uint_as_float(((u32)u) << 16); }
__device__ __forceinline__ u16 f2bf(float f) {
    u32 u = __float_as_uint(f);
    u += 0x7FFFu + ((u >> 16) & 1u);   // RNE
    return (u16)(u >> 16);
}
__device__ __forceinline__ u32 cvt_pk_bf16(float a, float b) {
    u32 r;
    asm("v_cvt_pk_bf16_f32 %0, %1, %2" : "=v"(r) : "v"(a), "v"(b));
    return r;
}
// elementwise product of two bf16 pairs -> bf16 pair
__device__ __forceinline__ u32 mul_bf_bf(u32 a2, u32 b2) {
    float lo = bf2f((u16)(a2 & 0xffffu)) * bf2f((u16)(b2 & 0xffffu));
    float hi = bf2f((u16)(a2 >> 16)) * bf2f((u16)(b2 >> 16));
    return cvt_pk_bf16(lo, hi);
}
__device__ __forceinline__ float fast_tanh(float x) {
    float e = __builtin_amdgcn_exp2f(x * 2.8853900817779268f);  // e^{2x}
    float r = __builtin_amdgcn_rcpf(e + 1.f);
    return __builtin_fmaf(-2.f, r, 1.f);
}

// ------------------- f32 -> bf16 pack (entity seed, eemb) -------------------------------
__global__ void k_cvt(const float* __restrict__ src, u16* __restrict__ dst, int n8) {
    int i = blockIdx.x * blockDim.x + threadIdx.x;
    if (i >= n8) return;
    float4 a = ((const float4*)src)[i * 2];
    float4 b = ((const float4*)src)[i * 2 + 1];
    u32 pk[4] = {cvt_pk_bf16(a.x, a.y), cvt_pk_bf16(a.z, a.w),
                 cvt_pk_bf16(b.x, b.y), cvt_pk_bf16(b.z, b.w)};
    ((uint4*)dst)[i] = *(uint4*)pk;
}

// ------------------- CSR build (once per call; head is hop-invariant) -------------------
__global__ void k_hist(const int* __restrict__ head, int E, int* __restrict__ counts) {
    int e = blockIdx.x * blockDim.x + threadIdx.x;
    if (e < E) atomicAdd(&counts[head[e]], 1);
}

__global__ void k_scan_a(const int* __restrict__ counts, int N, int* __restrict__ row_off,
                         int* __restrict__ partials) {
    __shared__ int sw[16];
    int i = blockIdx.x * 1024 + threadIdx.x;
    int v = (i < N) ? counts[i] : 0;
    int lane = threadIdx.x & 63, wid = threadIdx.x >> 6;
    int x = v;
    #pragma unroll
    for (int off = 1; off < 64; off <<= 1) {
        int t = __shfl_up(x, off);
        if (lane >= off) x += t;
    }
    if (lane == 63) sw[wid] = x;
    __syncthreads();
    if (threadIdx.x == 0) {
        int run = 0;
        for (int w0 = 0; w0 < 16; w0++) { int t = sw[w0]; sw[w0] = run; run += t; }
        partials[blockIdx.x] = run;
    }
    __syncthreads();
    if (i < N) row_off[i] = x - v + sw[wid];   // chunk-local exclusive
}
__global__ void k_scan_b(int* __restrict__ partials, int nch) {
    if (blockIdx.x == 0 && threadIdx.x == 0) {
        int run = 0;
        for (int c = 0; c < nch; c++) { int t = partials[c]; partials[c] = run; run += t; }
    }
}
__global__ void k_scan_c(int* __restrict__ row_off, const int* __restrict__ partials, int N, int E) {
    int i = blockIdx.x * 1024 + threadIdx.x;
    if (i < N) row_off[i] += partials[blockIdx.x];
    if (i == 0) row_off[N] = E;
}
__global__ void k_fill(const int* __restrict__ head, const int* __restrict__ tail,
                       const int* __restrict__ etype, int E, const int* __restrict__ row_off,
                       int* __restrict__ cursor, int* __restrict__ c_head,
                       int* __restrict__ c_tail, int* __restrict__ c_type) {
    int e = blockIdx.x * blockDim.x + threadIdx.x;
    if (e >= E) return;
    int h = head[e];
    int p = row_off[h] + atomicAdd(&cursor[h], 1);
    c_head[p] = h; c_tail[p] = tail[e]; c_type[p] = etype[e];
}

// node -> owning block (floor(start/CAP1)); block covers whole nodes, tile <= 128 edges
__global__ void k_blk(const int* __restrict__ row_off, int N,
                      int* __restrict__ blk_n0, int* __restrict__ blk_n1) {
    int n = blockIdx.x * blockDim.x + threadIdx.x;
    if (n >= N) return;
    int b = row_off[n] / CAP1;
    atomicMin(&blk_n0[b], n);
    atomicMax(&blk_n1[b], n + 1);
}
// pack per-block meta: {n0, n1, p0, span}
__global__ void k_meta(const int* __restrict__ blk_n0, const int* __restrict__ blk_n1,
                       const int* __restrict__ row_off, int NB, int4* __restrict__ meta) {
    int b = blockIdx.x * blockDim.x + threadIdx.x;
    if (b >= NB) return;
    int n0 = blk_n0[b];
    if (n0 == 0x7f7f7f7f) { meta[b] = make_int4(-1, 0, 0, 0); return; }
    int n1 = blk_n1[b];
    int p0 = row_off[n0];
    int span = row_off[n1] - p0;
    if (span > 128) span = 128;
    meta[b] = make_int4(n0, n1, p0, span);
}

// ------------------- weight prep -------------------------------------------------------
// swizzled transposed image (for LDS-linear copy + swizzled ds_read in k_qproj)
__global__ void k_prep_swz(const float* __restrict__ src, u16* __restrict__ dst_swz) {
    int idx = blockIdx.x * 256 + threadIdx.x;
    if (idx >= DD * DD) return;
    int n = idx >> 7, k = idx & 127;
    float v = src[k * DD + n];
    int byte = (n * 256 + k * 2) ^ ((n & 7) << 4);
    dst_swz[byte >> 1] = f2bf(v);
}
// plain transposed image (for direct global B-fragment reads in k_fused)
__global__ void k_prep_plain(const float* __restrict__ src, u16* __restrict__ dst) {
    int idx = blockIdx.x * 256 + threadIdx.x;
    if (idx >= DD * DD) return;
    int n = idx >> 7, k = idx & 127;
    dst[n * DD + k] = f2bf(src[k * DD + n]);
}

// ------------------- qh = aggb @ q_w  (bf16 out) via MFMA (round-10 proven) -------------
__global__ void __launch_bounds__(256) k_qproj(const u16* __restrict__ aggb,
                                               const uint4* __restrict__ qwT_swz,
                                               u16* __restrict__ qh, int N) {
    __shared__ u16 sA[DD * DD];    // 32 KB, swizzled bf16 rows
    __shared__ u16 sB[DD * DD];    // 32 KB, qwT swizzled
    int tid = threadIdx.x;
    {
        uint4* dst = (uint4*)sB;
        #pragma unroll
        for (int i = 0; i < 8; ++i) dst[i * 256 + tid] = qwT_swz[i * 256 + tid];
    }
    long base = (long)blockIdx.x * 128;
    int qq = tid & 3, er = tid >> 2;
    #pragma unroll
    for (int pass = 0; pass < 2; ++pass) {
        int rloc = pass * 64 + er;
        long n = base + rloc;
        int d0 = qq * 32;
        __align__(16) uint4 pk[4];
        if (n < N) {
            const uint4* ar = (const uint4*)(aggb + (size_t)n * DD + d0);
            #pragma unroll
            for (int c = 0; c < 4; ++c) pk[c] = ar[c];
        } else {
            #pragma unroll
            for (int c = 0; c < 4; ++c) pk[c] = (uint4){0u, 0u, 0u, 0u};
        }
        char* basep = (char*)sA;
        #pragma unroll
        for (int c = 0; c < 4; ++c) {
            int byte = (rloc * 256 + d0 * 2 + c * 16) ^ ((rloc & 7) << 4);
            *(uint4*)(basep + byte) = pk[c];
        }
    }
    __syncthreads();
    int lane = tid & 63, wid = tid >> 6;
    int lr = lane & 15, lg = lane >> 4;
    int rgbase = wid * 32;
    f32x4 acc[2][8];
    #pragma unroll
    for (int g = 0; g < 2; ++g)
        #pragma unroll
        for (int t = 0; t < 8; ++t) acc[g][t] = (f32x4){0.f, 0.f, 0.f, 0.f};
    const char* ab_ = (const char*)sA;
    const char* bb_ = (const char*)sB;
    int sw = (lr & 7) << 4;
    #pragma unroll
    for (int kc = 0; kc < 4; ++kc) {
        int koffb = kc * 64 + lg * 16;
        int r0 = rgbase + lr;
        bf16x8 a0 = *(const bf16x8*)(ab_ + ((r0 * 256 + koffb) ^ sw));
        bf16x8 a1 = *(const bf16x8*)(ab_ + (((r0 + 16) * 256 + koffb) ^ sw));
        #pragma unroll
        for (int t = 0; t < 8; ++t) {
            int n = t * 16 + lr;
            bf16x8 b = *(const bf16x8*)(bb_ + ((n * 256 + koffb) ^ sw));
            acc[0][t] = __builtin_amdgcn_mfma_f32_16x16x32_bf16(a0, b, acc[0][t], 0, 0, 0);
            acc[1][t] = __builtin_amdgcn_mfma_f32_16x16x32_bf16(a1, b, acc[1][t], 0, 0, 0);
        }
    }
    #pragma unroll
    for (int g = 0; g < 2; ++g)
        #pragma unroll
        for (int r = 0; r < 4; ++r) {
            long row = base + rgbase + g * 16 + lg * 4 + r;
            if (row < N) {
                u16* qrow = qh + (size_t)row * DD + lr;
                #pragma unroll
                for (int t = 0; t < 8; ++t) qrow[t * 16] = f2bf(acc[g][t][r]);
            }
        }
}

// ------------------- fused: att + segment softmax + weighted agg + normalize ------------
// Block owns nodes [n0,n1), tile = their CSR span (<=128 edges). 256 threads, 4 waves.
__global__ void __launch_bounds__(256, 4) k_fused(
        const u16* __restrict__ aggb, const u16* __restrict__ eembb,
        const u16* __restrict__ kwT, const u16* __restrict__ qh,
        const int* __restrict__ c_head, const int* __restrict__ c_tail,
        const int* __restrict__ c_type, const int* __restrict__ row_off,
        const int4* __restrict__ meta, const float* __restrict__ entity,
        u16* __restrict__ aggb_next, float* __restrict__ outacc, int mode, int E) {
    __shared__ u16 sX[DD * DD];    // 32 KB, swizzled bf16 X rows
    __shared__ float satt[128];
    int4 mt = meta[blockIdx.x];
    if (mt.x < 0) return;                  // no nodes own this window
    int n0 = mt.x, n1 = mt.y, p0 = mt.z, span = mt.w;
    int tid = threadIdx.x;
    int qq = tid & 3, er = tid >> 2;       // 4 threads/edge, 32 dims each
    int d0 = qq * 32;
    // ---- batched stage: indices for both passes, then ALL gathers in flight ----
    {
        int pclamp = min(p0, E - 1);
        int tl[2], rl[2];
        bool valid[2];
        #pragma unroll
        for (int pass = 0; pass < 2; ++pass) {
            int eloc = pass * 64 + er;
            valid[pass] = (eloc < span);
            int p = valid[pass] ? p0 + eloc : pclamp;   // in-window clamp: no junk row fetch
            tl[pass] = c_tail[p];
            rl[pass] = c_type[p];
        }
        uint4 av[2][4], rv[2][4];
        #pragma unroll
        for (int pass = 0; pass < 2; ++pass) {
            const uint4* ar = (const uint4*)(aggb + (size_t)tl[pass] * DD + d0);
            const uint4* rr = (const uint4*)(eembb + (size_t)rl[pass] * DD + d0);
            #pragma unroll
            for (int c = 0; c < 4; ++c) { av[pass][c] = ar[c]; rv[pass][c] = rr[c]; }
        }
        char* base = (char*)sX;
        #pragma unroll
        for (int pass = 0; pass < 2; ++pass) {
            int eloc = pass * 64 + er;
            __align__(16) u32 pk[4];
            #pragma unroll
            for (int c = 0; c < 4; ++c) {
                if (valid[pass]) {
                    pk[0] = mul_bf_bf(av[pass][c].x, rv[pass][c].x);
                    pk[1] = mul_bf_bf(av[pass][c].y, rv[pass][c].y);
                    pk[2] = mul_bf_bf(av[pass][c].z, rv[pass][c].z);
                    pk[3] = mul_bf_bf(av[pass][c].w, rv[pass][c].w);
                } else {
                    pk[0] = pk[1] = pk[2] = pk[3] = 0u;
                }
                int byte = (eloc * 256 + d0 * 2 + c * 16) ^ ((eloc & 7) << 4);
                *(uint4*)(base + byte) = *(const uint4*)pk;
            }
        }
    }
    __syncthreads();
    // ---- S = X @ kwT^T via MFMA (t-outer, acc pair live), tanh + qh dot -> satt ----
    int lane = tid & 63, wid = tid >> 6;
    int lr = lane & 15, lg = lane >> 4;
    int egbase = wid * 32;
    const char* xb_ = (const char*)sX;
    int sw = (lr & 7) << 4;
    bf16x8 afrag[2][4];
    #pragma unroll
    for (int kc = 0; kc < 4; ++kc) {
        int koffb = kc * 64 + lg * 16;
        int r0 = egbase + lr;
        afrag[0][kc] = *(const bf16x8*)(xb_ + ((r0 * 256 + koffb) ^ sw));
        afrag[1][kc] = *(const bf16x8*)(xb_ + (((r0 + 16) * 256 + koffb) ^ sw));
    }
    int hh[8];
    #pragma unroll
    for (int g = 0; g < 2; ++g)
        #pragma unroll
        for (int r = 0; r < 4; ++r) {
            int eloc = egbase + g * 16 + lg * 4 + r;
            hh[g * 4 + r] = (eloc < span) ? c_head[p0 + eloc] : 0;
        }
    float attv[8] = {0.f, 0.f, 0.f, 0.f, 0.f, 0.f, 0.f, 0.f};
    #pragma unroll
    for (int t = 0; t < 8; ++t) {
        f32x4 acc0 = (f32x4){0.f, 0.f, 0.f, 0.f};
        f32x4 acc1 = (f32x4){0.f, 0.f, 0.f, 0.f};
        int n = t * 16 + lr;
        #pragma unroll
        for (int kc = 0; kc < 4; ++kc) {
            int koffe = kc * 32 + lg * 8;
            bf16x8 b = *(const bf16x8*)(kwT + n * DD + koffe);
            acc0 = __builtin_amdgcn_mfma_f32_16x16x32_bf16(afrag[0][kc], b, acc0, 0, 0, 0);
            acc1 = __builtin_amdgcn_mfma_f32_16x16x32_bf16(afrag[1][kc], b, acc1, 0, 0, 0);
        }
        // C/D: col = lane&15, row = (lane>>4)*4 + reg
        #pragma unroll
        for (int r = 0; r < 4; ++r) {
            attv[r]     += fast_tanh(acc0[r]) * bf2f(qh[(size_t)hh[r] * DD + t * 16 + lr]);
            attv[4 + r] += fast_tanh(acc1[r]) * bf2f(qh[(size_t)hh[4 + r] * DD + t * 16 + lr]);
        }
    }
    #pragma unroll
    for (int off = 1; off < 16; off <<= 1) {
        #pragma unroll
        for (int i = 0; i < 8; ++i) attv[i] += __shfl_xor(attv[i], off);
    }
    if (lr == 0) {
        #pragma unroll
        for (int g = 0; g < 2; ++g)
            #pragma unroll
            for (int r = 0; r < 4; ++r) {
                int eloc = egbase + g * 16 + lg * 4 + r;
                if (eloc < span) satt[eloc] = attv[g * 4 + r];
            }
    }
    __syncthreads();
    // ---- per-node: lane-parallel EXACT max, weighted sum of LDS X rows, normalize ----
    for (int n = n0 + wid; n < n1; n += 4) {
        int s0 = row_off[n] - p0;
        int s1 = min(row_off[n + 1] - p0, 128);
        float a0 = 0.f, a1 = 0.f;
        if (s1 > s0) {
            float mv = -1e30f;
            int pp = s0 + lane;
            if (pp < s1) mv = satt[pp];
            if (pp + 64 < s1) mv = fmaxf(mv, satt[pp + 64]);
            #pragma unroll
            for (int off = 1; off < 64; off <<= 1) mv = fmaxf(mv, __shfl_xor(mv, off));
            #pragma unroll 2
            for (int p = s0; p < s1; ++p) {
                float wgt = __expf(satt[p] - mv);
                int byte = (p * 256 + lane * 4) ^ ((p & 7) << 4);
                u32 xv = *(const u32*)((const char*)sX + byte);
                a0 += wgt * bf2f((u16)(xv & 0xffffu));
                a1 += wgt * bf2f((u16)(xv >> 16));
            }
            float s = a0 * a0 + a1 * a1;
            #pragma unroll
            for (int off = 1; off < 64; off <<= 1) s += __shfl_xor(s, off);
            float sc = 1.f / fmaxf(sqrtf(s), 1e-12f);
            a0 *= sc; a1 *= sc;
        }
        size_t idx = (size_t)n * DD + lane * 2;
        *(u32*)(aggb_next + idx) = cvt_pk_bf16(a0, a1);
        float o0, o1;
        if (mode == 0) { o0 = a0; o1 = a1; }
        else { o0 = outacc[idx] + a0; o1 = outacc[idx + 1] + a1; }
        if (mode == 2) { o0 += 3.f * entity[idx]; o1 += 3.f * entity[idx + 1]; }
        outacc[idx] = o0; outacc[idx + 1] = o1;
    }
}

extern "C" void kernel_launch(void* const* d_in, const int* in_sizes, int n_in,
                              void* d_out, int out_size, void* d_ws, size_t ws_size,
                              hipStream_t stream) {
    const float* entity = (const float*)d_in[0];
    const float* eemb   = (const float*)d_in[1];
    const float* qw     = (const float*)d_in[2];
    const float* kw     = (const float*)d_in[3];
    const int*   eidx   = (const int*)d_in[4];
    const int*   etype  = (const int*)d_in[5];
    const int N = in_sizes[0] / DD;
    const int E = in_sizes[5];
    const int NREL = in_sizes[1] / DD;
    const int* head = eidx;
    const int* tail = eidx + E;
    const int NB = E / CAP1 + 2;

    // workspace carve (~113 MB)
    char* w = (char*)d_ws;
    auto carve = [&](size_t bytes) -> void* {
        void* p = (void*)w;
        w += ((bytes + 255) / 256) * 256;
        return p;
    };
    u16* aggbA     = (u16*)carve((size_t)N * DD * 2);
    u16* aggbB     = (u16*)carve((size_t)N * DD * 2);
    u16* aggb0     = (u16*)carve((size_t)N * DD * 2);
    u16* qh        = (u16*)carve((size_t)N * DD * 2);
    u16* eembb     = (u16*)carve((size_t)NREL * DD * 2);
    int* counts    = (int*)carve((size_t)N * 4);
    int* row_off   = (int*)carve((size_t)(N + 1) * 4);
    int* cursor    = (int*)carve((size_t)N * 4);
    int* c_head    = (int*)carve((size_t)E * 4);
    int* c_tail    = (int*)carve((size_t)E * 4);
    int* c_type    = (int*)carve((size_t)E * 4);
    u16* qwT_swz   = (u16*)carve((size_t)DD * DD * 2);
    u16* kwT       = (u16*)carve((size_t)DD * DD * 2);
    int* blk_n0    = (int*)carve((size_t)NB * 4);
    int* blk_n1    = (int*)carve((size_t)NB * 4);
    int4* meta     = (int4*)carve((size_t)NB * 16);
    int* partials  = (int*)carve(4096);
    (void)ws_size; (void)n_in; (void)out_size;

    hipMemsetAsync(counts, 0, (size_t)N * 4, stream);
    hipMemsetAsync(cursor, 0, (size_t)N * 4, stream);
    hipMemsetAsync(blk_n0, 0x7f, (size_t)NB * 4, stream);
    hipMemsetAsync(blk_n1, 0, (size_t)NB * 4, stream);
    k_prep_swz<<<(DD * DD + 255) / 256, 256, 0, stream>>>(qw, qwT_swz);
    k_prep_plain<<<(DD * DD + 255) / 256, 256, 0, stream>>>(kw, kwT);
    int n8 = N * DD / 8;
    k_cvt<<<(n8 + 255) / 256, 256, 0, stream>>>(entity, aggb0, n8);
    int r8 = NREL * DD / 8;
    k_cvt<<<(r8 + 255) / 256, 256, 0, stream>>>(eemb, eembb, r8);
    k_hist<<<(E + 255) / 256, 256, 0, stream>>>(head, E, counts);
    int nch = (N + 1023) / 1024;
    k_scan_a<<<nch, 1024, 0, stream>>>(counts, N, row_off, partials);
    k_scan_b<<<1, 64, 0, stream>>>(partials, nch);
    k_scan_c<<<nch, 1024, 0, stream>>>(row_off, partials, N, E);
    k_fill<<<(E + 255) / 256, 256, 0, stream>>>(head, tail, etype, E, row_off, cursor,
                                                c_head, c_tail, c_type);
    k_blk<<<(N + 255) / 256, 256, 0, stream>>>(row_off, N, blk_n0, blk_n1);
    k_meta<<<(NB + 255) / 256, 256, 0, stream>>>(blk_n0, blk_n1, row_off, NB, meta);

    const u16* cur = aggb0;
    u16* bufs[2] = {aggbA, aggbB};
    for (int hop = 0; hop < 3; hop++) {
        k_qproj<<<(N + 127) / 128, 256, 0, stream>>>(cur, (const uint4*)qwT_swz, qh, N);
        u16* nxt = bufs[hop & 1];
        int mode = (hop == 0) ? 0 : ((hop == 2) ? 2 : 1);
        k_fused<<<NB, 256, 0, stream>>>(cur, eembb, kwT, qh, c_head, c_tail, c_type,
                                        row_off, meta, entity,
                                        nxt, (float*)d_out, mode, E);
        cur = nxt;
    }
}

// Round 15
// 614.295 us; speedup vs baseline: 2.0557x; 1.0375x over previous
//
#include <hip/hip_runtime.h>

// KG attention, 3 hops.  (r14 best + fold output accumulation into hop-2 epilogue)
//  - softmax denom & cnt cancel under L2 normalize: agg_next = normalize(sum_e exp(att-m)*X_e)
//  - agg in bf16 between hops; eemb pre-converted to bf16
//  - CSR by head; nodes partitioned into blocks by row_off[n]/96 -> window <= 128 edges
//  - k_fused (256 thr, 4 waves): batched gather stage -> S=X@kwT MFMA -> att in LDS ->
//    lane-parallel segment max -> weighted sum from LDS X -> normalize
//  - output: hops 0/1 write only bf16 agg; hop 2 computes out = 3*entity + a1 + a2 + a3
//    (independent reads, no RMW chain, no extra kernel)
// Workspace ~113 MB.

#define DD 128
#define CAP1 96

typedef unsigned short u16;
typedef unsigned int u32;
typedef __attribute__((ext_vector_type(8))) __bf16 bf16x8;
typedef __attribute__((ext_vector_type(4))) float f32x4;

__device__ __forceinline__ float bf2f(u16 u) { return __uint_as_float(((u32)u) << 16); }
__device__ __forceinline__ u16 f2bf(float f) {
    u32 u = __float_as_uint(f);
    u += 0x7FFFu + ((u >> 16) & 1u);   // RNE
    return (u16)(u >> 16);
}
__device__ __forceinline__ u32 cvt_pk_bf16(float a, float b) {
    u32 r;
    asm("v_cvt_pk_bf16_f32 %0, %1, %2" : "=v"(r) : "v"(a), "v"(b));
    return r;
}
// elementwise product of two bf16 pairs -> bf16 pair
__device__ __forceinline__ u32 mul_bf_bf(u32 a2, u32 b2) {
    float lo = bf2f((u16)(a2 & 0xffffu)) * bf2f((u16)(b2 & 0xffffu));
    float hi = bf2f((u16)(a2 >> 16)) * bf2f((u16)(b2 >> 16));
    return cvt_pk_bf16(lo, hi);
}
__device__ __forceinline__ float fast_tanh(float x) {
    float e = __builtin_amdgcn_exp2f(x * 2.8853900817779268f);  // e^{2x}
    float r = __builtin_amdgcn_rcpf(e + 1.f);
    return __builtin_fmaf(-2.f, r, 1.f);
}

// ------------------- f32 -> bf16 pack (entity seed, eemb) -------------------------------
__global__ void k_cvt(const float* __restrict__ src, u16* __restrict__ dst, int n8) {
    int i = blockIdx.x * blockDim.x + threadIdx.x;
    if (i >= n8) return;
    float4 a = ((const float4*)src)[i * 2];
    float4 b = ((const float4*)src)[i * 2 + 1];
    u32 pk[4] = {cvt_pk_bf16(a.x, a.y), cvt_pk_bf16(a.z, a.w),
                 cvt_pk_bf16(b.x, b.y), cvt_pk_bf16(b.z, b.w)};
    ((uint4*)dst)[i] = *(uint4*)pk;
}

// ------------------- CSR build (once per call; head is hop-invariant) -------------------
__global__ void k_hist(const int* __restrict__ head, int E, int* __restrict__ counts) {
    int e = blockIdx.x * blockDim.x + threadIdx.x;
    if (e < E) atomicAdd(&counts[head[e]], 1);
}

__global__ void k_scan_a(const int* __restrict__ counts, int N, int* __restrict__ row_off,
                         int* __restrict__ partials) {
    __shared__ int sw[16];
    int i = blockIdx.x * 1024 + threadIdx.x;
    int v = (i < N) ? counts[i] : 0;
    int lane = threadIdx.x & 63, wid = threadIdx.x >> 6;
    int x = v;
    #pragma unroll
    for (int off = 1; off < 64; off <<= 1) {
        int t = __shfl_up(x, off);
        if (lane >= off) x += t;
    }
    if (lane == 63) sw[wid] = x;
    __syncthreads();
    if (threadIdx.x == 0) {
        int run = 0;
        for (int w0 = 0; w0 < 16; w0++) { int t = sw[w0]; sw[w0] = run; run += t; }
        partials[blockIdx.x] = run;
    }
    __syncthreads();
    if (i < N) row_off[i] = x - v + sw[wid];   // chunk-local exclusive
}
__global__ void k_scan_b(int* __restrict__ partials, int nch) {
    if (blockIdx.x == 0 && threadIdx.x == 0) {
        int run = 0;
        for (int c = 0; c < nch; c++) { int t = partials[c]; partials[c] = run; run += t; }
    }
}
__global__ void k_scan_c(int* __restrict__ row_off, const int* __restrict__ partials, int N, int E) {
    int i = blockIdx.x * 1024 + threadIdx.x;
    if (i < N) row_off[i] += partials[blockIdx.x];
    if (i == 0) row_off[N] = E;
}
__global__ void k_fill(const int* __restrict__ head, const int* __restrict__ tail,
                       const int* __restrict__ etype, int E, const int* __restrict__ row_off,
                       int* __restrict__ cursor, int* __restrict__ c_head,
                       int* __restrict__ c_tail, int* __restrict__ c_type) {
    int e = blockIdx.x * blockDim.x + threadIdx.x;
    if (e >= E) return;
    int h = head[e];
    int p = row_off[h] + atomicAdd(&cursor[h], 1);
    c_head[p] = h; c_tail[p] = tail[e]; c_type[p] = etype[e];
}

// node -> owning block (floor(start/CAP1)); block covers whole nodes, tile <= 128 edges
__global__ void k_blk(const int* __restrict__ row_off, int N,
                      int* __restrict__ blk_n0, int* __restrict__ blk_n1) {
    int n = blockIdx.x * blockDim.x + threadIdx.x;
    if (n >= N) return;
    int b = row_off[n] / CAP1;
    atomicMin(&blk_n0[b], n);
    atomicMax(&blk_n1[b], n + 1);
}
// pack per-block meta: {n0, n1, p0, span}
__global__ void k_meta(const int* __restrict__ blk_n0, const int* __restrict__ blk_n1,
                       const int* __restrict__ row_off, int NB, int4* __restrict__ meta) {
    int b = blockIdx.x * blockDim.x + threadIdx.x;
    if (b >= NB) return;
    int n0 = blk_n0[b];
    if (n0 == 0x7f7f7f7f) { meta[b] = make_int4(-1, 0, 0, 0); return; }
    int n1 = blk_n1[b];
    int p0 = row_off[n0];
    int span = row_off[n1] - p0;
    if (span > 128) span = 128;
    meta[b] = make_int4(n0, n1, p0, span);
}

// ------------------- weight prep -------------------------------------------------------
// swizzled transposed image (for LDS-linear copy + swizzled ds_read in k_qproj)
__global__ void k_prep_swz(const float* __restrict__ src, u16* __restrict__ dst_swz) {
    int idx = blockIdx.x * 256 + threadIdx.x;
    if (idx >= DD * DD) return;
    int n = idx >> 7, k = idx & 127;
    float v = src[k * DD + n];
    int byte = (n * 256 + k * 2) ^ ((n & 7) << 4);
    dst_swz[byte >> 1] = f2bf(v);
}
// plain transposed image (for direct global B-fragment reads in k_fused)
__global__ void k_prep_plain(const float* __restrict__ src, u16* __restrict__ dst) {
    int idx = blockIdx.x * 256 + threadIdx.x;
    if (idx >= DD * DD) return;
    int n = idx >> 7, k = idx & 127;
    dst[n * DD + k] = f2bf(src[k * DD + n]);
}

// ------------------- qh = aggb @ q_w  (bf16 out) via MFMA (round-10 proven) -------------
__global__ void __launch_bounds__(256) k_qproj(const u16* __restrict__ aggb,
                                               const uint4* __restrict__ qwT_swz,
                                               u16* __restrict__ qh, int N) {
    __shared__ u16 sA[DD * DD];    // 32 KB, swizzled bf16 rows
    __shared__ u16 sB[DD * DD];    // 32 KB, qwT swizzled
    int tid = threadIdx.x;
    {
        uint4* dst = (uint4*)sB;
        #pragma unroll
        for (int i = 0; i < 8; ++i) dst[i * 256 + tid] = qwT_swz[i * 256 + tid];
    }
    long base = (long)blockIdx.x * 128;
    int qq = tid & 3, er = tid >> 2;
    #pragma unroll
    for (int pass = 0; pass < 2; ++pass) {
        int rloc = pass * 64 + er;
        long n = base + rloc;
        int d0 = qq * 32;
        __align__(16) uint4 pk[4];
        if (n < N) {
            const uint4* ar = (const uint4*)(aggb + (size_t)n * DD + d0);
            #pragma unroll
            for (int c = 0; c < 4; ++c) pk[c] = ar[c];
        } else {
            #pragma unroll
            for (int c = 0; c < 4; ++c) pk[c] = (uint4){0u, 0u, 0u, 0u};
        }
        char* basep = (char*)sA;
        #pragma unroll
        for (int c = 0; c < 4; ++c) {
            int byte = (rloc * 256 + d0 * 2 + c * 16) ^ ((rloc & 7) << 4);
            *(uint4*)(basep + byte) = pk[c];
        }
    }
    __syncthreads();
    int lane = tid & 63, wid = tid >> 6;
    int lr = lane & 15, lg = lane >> 4;
    int rgbase = wid * 32;
    f32x4 acc[2][8];
    #pragma unroll
    for (int g = 0; g < 2; ++g)
        #pragma unroll
        for (int t = 0; t < 8; ++t) acc[g][t] = (f32x4){0.f, 0.f, 0.f, 0.f};
    const char* ab_ = (const char*)sA;
    const char* bb_ = (const char*)sB;
    int sw = (lr & 7) << 4;
    #pragma unroll
    for (int kc = 0; kc < 4; ++kc) {
        int koffb = kc * 64 + lg * 16;
        int r0 = rgbase + lr;
        bf16x8 a0 = *(const bf16x8*)(ab_ + ((r0 * 256 + koffb) ^ sw));
        bf16x8 a1 = *(const bf16x8*)(ab_ + (((r0 + 16) * 256 + koffb) ^ sw));
        #pragma unroll
        for (int t = 0; t < 8; ++t) {
            int n = t * 16 + lr;
            bf16x8 b = *(const bf16x8*)(bb_ + ((n * 256 + koffb) ^ sw));
            acc[0][t] = __builtin_amdgcn_mfma_f32_16x16x32_bf16(a0, b, acc[0][t], 0, 0, 0);
            acc[1][t] = __builtin_amdgcn_mfma_f32_16x16x32_bf16(a1, b, acc[1][t], 0, 0, 0);
        }
    }
    #pragma unroll
    for (int g = 0; g < 2; ++g)
        #pragma unroll
        for (int r = 0; r < 4; ++r) {
            long row = base + rgbase + g * 16 + lg * 4 + r;
            if (row < N) {
                u16* qrow = qh + (size_t)row * DD + lr;
                #pragma unroll
                for (int t = 0; t < 8; ++t) qrow[t * 16] = f2bf(acc[g][t][r]);
            }
        }
}

// ------------------- fused: att + segment softmax + weighted agg + normalize ------------
// Block owns nodes [n0,n1), tile = their CSR span (<=128 edges). 256 threads, 4 waves.
// mode 0/1: write aggb_next (bf16). mode 2: write out = 3*entity + a1 + a2 + a3 (f32).
__global__ void __launch_bounds__(256, 4) k_fused(
        const u16* __restrict__ aggb, const u16* __restrict__ eembb,
        const u16* __restrict__ kwT, const u16* __restrict__ qh,
        const int* __restrict__ c_head, const int* __restrict__ c_tail,
        const int* __restrict__ c_type, const int* __restrict__ row_off,
        const int4* __restrict__ meta, const float* __restrict__ entity,
        const u16* __restrict__ a1p, const u16* __restrict__ a2p,
        u16* __restrict__ aggb_next, float* __restrict__ outp, int mode, int E) {
    __shared__ u16 sX[DD * DD];    // 32 KB, swizzled bf16 X rows
    __shared__ float satt[128];
    int4 mt = meta[blockIdx.x];
    if (mt.x < 0) return;                  // no nodes own this window
    int n0 = mt.x, n1 = mt.y, p0 = mt.z, span = mt.w;
    int tid = threadIdx.x;
    int qq = tid & 3, er = tid >> 2;       // 4 threads/edge, 32 dims each
    int d0 = qq * 32;
    // ---- batched stage: indices for both passes, then ALL gathers in flight ----
    {
        int pclamp = min(p0, E - 1);
        int tl[2], rl[2];
        bool valid[2];
        #pragma unroll
        for (int pass = 0; pass < 2; ++pass) {
            int eloc = pass * 64 + er;
            valid[pass] = (eloc < span);
            int p = valid[pass] ? p0 + eloc : pclamp;   // in-window clamp
            tl[pass] = c_tail[p];
            rl[pass] = c_type[p];
        }
        uint4 av[2][4], rv[2][4];
        #pragma unroll
        for (int pass = 0; pass < 2; ++pass) {
            const uint4* ar = (const uint4*)(aggb + (size_t)tl[pass] * DD + d0);
            const uint4* rr = (const uint4*)(eembb + (size_t)rl[pass] * DD + d0);
            #pragma unroll
            for (int c = 0; c < 4; ++c) { av[pass][c] = ar[c]; rv[pass][c] = rr[c]; }
        }
        char* base = (char*)sX;
        #pragma unroll
        for (int pass = 0; pass < 2; ++pass) {
            int eloc = pass * 64 + er;
            __align__(16) u32 pk[4];
            #pragma unroll
            for (int c = 0; c < 4; ++c) {
                if (valid[pass]) {
                    pk[0] = mul_bf_bf(av[pass][c].x, rv[pass][c].x);
                    pk[1] = mul_bf_bf(av[pass][c].y, rv[pass][c].y);
                    pk[2] = mul_bf_bf(av[pass][c].z, rv[pass][c].z);
                    pk[3] = mul_bf_bf(av[pass][c].w, rv[pass][c].w);
                } else {
                    pk[0] = pk[1] = pk[2] = pk[3] = 0u;
                }
                int byte = (eloc * 256 + d0 * 2 + c * 16) ^ ((eloc & 7) << 4);
                *(uint4*)(base + byte) = *(const uint4*)pk;
            }
        }
    }
    __syncthreads();
    // ---- S = X @ kwT^T via MFMA (t-outer, acc pair live), tanh + qh dot -> satt ----
    int lane = tid & 63, wid = tid >> 6;
    int lr = lane & 15, lg = lane >> 4;
    int egbase = wid * 32;
    const char* xb_ = (const char*)sX;
    int sw = (lr & 7) << 4;
    bf16x8 afrag[2][4];
    #pragma unroll
    for (int kc = 0; kc < 4; ++kc) {
        int koffb = kc * 64 + lg * 16;
        int r0 = egbase + lr;
        afrag[0][kc] = *(const bf16x8*)(xb_ + ((r0 * 256 + koffb) ^ sw));
        afrag[1][kc] = *(const bf16x8*)(xb_ + (((r0 + 16) * 256 + koffb) ^ sw));
    }
    int hh[8];
    #pragma unroll
    for (int g = 0; g < 2; ++g)
        #pragma unroll
        for (int r = 0; r < 4; ++r) {
            int eloc = egbase + g * 16 + lg * 4 + r;
            hh[g * 4 + r] = (eloc < span) ? c_head[p0 + eloc] : 0;
        }
    float attv[8] = {0.f, 0.f, 0.f, 0.f, 0.f, 0.f, 0.f, 0.f};
    #pragma unroll
    for (int t = 0; t < 8; ++t) {
        f32x4 acc0 = (f32x4){0.f, 0.f, 0.f, 0.f};
        f32x4 acc1 = (f32x4){0.f, 0.f, 0.f, 0.f};
        int n = t * 16 + lr;
        #pragma unroll
        for (int kc = 0; kc < 4; ++kc) {
            int koffe = kc * 32 + lg * 8;
            bf16x8 b = *(const bf16x8*)(kwT + n * DD + koffe);
            acc0 = __builtin_amdgcn_mfma_f32_16x16x32_bf16(afrag[0][kc], b, acc0, 0, 0, 0);
            acc1 = __builtin_amdgcn_mfma_f32_16x16x32_bf16(afrag[1][kc], b, acc1, 0, 0, 0);
        }
        // C/D: col = lane&15, row = (lane>>4)*4 + reg
        #pragma unroll
        for (int r = 0; r < 4; ++r) {
            attv[r]     += fast_tanh(acc0[r]) * bf2f(qh[(size_t)hh[r] * DD + t * 16 + lr]);
            attv[4 + r] += fast_tanh(acc1[r]) * bf2f(qh[(size_t)hh[4 + r] * DD + t * 16 + lr]);
        }
    }
    #pragma unroll
    for (int off = 1; off < 16; off <<= 1) {
        #pragma unroll
        for (int i = 0; i < 8; ++i) attv[i] += __shfl_xor(attv[i], off);
    }
    if (lr == 0) {
        #pragma unroll
        for (int g = 0; g < 2; ++g)
            #pragma unroll
            for (int r = 0; r < 4; ++r) {
                int eloc = egbase + g * 16 + lg * 4 + r;
                if (eloc < span) satt[eloc] = attv[g * 4 + r];
            }
    }
    __syncthreads();
    // ---- per-node: lane-parallel EXACT max, weighted sum of LDS X rows, normalize ----
    for (int n = n0 + wid; n < n1; n += 4) {
        int s0 = row_off[n] - p0;
        int s1 = min(row_off[n + 1] - p0, 128);
        float a0 = 0.f, a1 = 0.f;
        if (s1 > s0) {
            float mv = -1e30f;
            int pp = s0 + lane;
            if (pp < s1) mv = satt[pp];
            if (pp + 64 < s1) mv = fmaxf(mv, satt[pp + 64]);
            #pragma unroll
            for (int off = 1; off < 64; off <<= 1) mv = fmaxf(mv, __shfl_xor(mv, off));
            #pragma unroll 2
            for (int p = s0; p < s1; ++p) {
                float wgt = __expf(satt[p] - mv);
                int byte = (p * 256 + lane * 4) ^ ((p & 7) << 4);
                u32 xv = *(const u32*)((const char*)sX + byte);
                a0 += wgt * bf2f((u16)(xv & 0xffffu));
                a1 += wgt * bf2f((u16)(xv >> 16));
            }
            float s = a0 * a0 + a1 * a1;
            #pragma unroll
            for (int off = 1; off < 64; off <<= 1) s += __shfl_xor(s, off);
            float sc = 1.f / fmaxf(sqrtf(s), 1e-12f);
            a0 *= sc; a1 *= sc;
        }
        size_t idx = (size_t)n * DD + lane * 2;
        if (mode != 2) {
            *(u32*)(aggb_next + idx) = cvt_pk_bf16(a0, a1);
        } else {
            u32 x1 = *(const u32*)(a1p + idx);
            u32 x2 = *(const u32*)(a2p + idx);
            float2 ev = *(const float2*)(entity + idx);
            float o0 = __builtin_fmaf(3.f, ev.x,
                         bf2f((u16)(x1 & 0xffffu)) + bf2f((u16)(x2 & 0xffffu)) + a0);
            float o1 = __builtin_fmaf(3.f, ev.y,
                         bf2f((u16)(x1 >> 16)) + bf2f((u16)(x2 >> 16)) + a1);
            float2 ov; ov.x = o0; ov.y = o1;
            *(float2*)(outp + idx) = ov;
        }
    }
}

extern "C" void kernel_launch(void* const* d_in, const int* in_sizes, int n_in,
                              void* d_out, int out_size, void* d_ws, size_t ws_size,
                              hipStream_t stream) {
    const float* entity = (const float*)d_in[0];
    const float* eemb   = (const float*)d_in[1];
    const float* qw     = (const float*)d_in[2];
    const float* kw     = (const float*)d_in[3];
    const int*   eidx   = (const int*)d_in[4];
    const int*   etype  = (const int*)d_in[5];
    const int N = in_sizes[0] / DD;
    const int E = in_sizes[5];
    const int NREL = in_sizes[1] / DD;
    const int* head = eidx;
    const int* tail = eidx + E;
    const int NB = E / CAP1 + 2;

    // workspace carve (~113 MB)
    char* w = (char*)d_ws;
    auto carve = [&](size_t bytes) -> void* {
        void* p = (void*)w;
        w += ((bytes + 255) / 256) * 256;
        return p;
    };
    u16* aggbA     = (u16*)carve((size_t)N * DD * 2);
    u16* aggbB     = (u16*)carve((size_t)N * DD * 2);
    u16* aggb0     = (u16*)carve((size_t)N * DD * 2);
    u16* qh        = (u16*)carve((size_t)N * DD * 2);
    u16* eembb     = (u16*)carve((size_t)NREL * DD * 2);
    int* counts    = (int*)carve((size_t)N * 4);
    int* row_off   = (int*)carve((size_t)(N + 1) * 4);
    int* cursor    = (int*)carve((size_t)N * 4);
    int* c_head    = (int*)carve((size_t)E * 4);
    int* c_tail    = (int*)carve((size_t)E * 4);
    int* c_type    = (int*)carve((size_t)E * 4);
    u16* qwT_swz   = (u16*)carve((size_t)DD * DD * 2);
    u16* kwT       = (u16*)carve((size_t)DD * DD * 2);
    int* blk_n0    = (int*)carve((size_t)NB * 4);
    int* blk_n1    = (int*)carve((size_t)NB * 4);
    int4* meta     = (int4*)carve((size_t)NB * 16);
    int* partials  = (int*)carve(4096);
    (void)ws_size; (void)n_in; (void)out_size;

    hipMemsetAsync(counts, 0, (size_t)N * 4, stream);
    hipMemsetAsync(cursor, 0, (size_t)N * 4, stream);
    hipMemsetAsync(blk_n0, 0x7f, (size_t)NB * 4, stream);
    hipMemsetAsync(blk_n1, 0, (size_t)NB * 4, stream);
    k_prep_swz<<<(DD * DD + 255) / 256, 256, 0, stream>>>(qw, qwT_swz);
    k_prep_plain<<<(DD * DD + 255) / 256, 256, 0, stream>>>(kw, kwT);
    int n8 = N * DD / 8;
    k_cvt<<<(n8 + 255) / 256, 256, 0, stream>>>(entity, aggb0, n8);
    int r8 = NREL * DD / 8;
    k_cvt<<<(r8 + 255) / 256, 256, 0, stream>>>(eemb, eembb, r8);
    k_hist<<<(E + 255) / 256, 256, 0, stream>>>(head, E, counts);
    int nch = (N + 1023) / 1024;
    k_scan_a<<<nch, 1024, 0, stream>>>(counts, N, row_off, partials);
    k_scan_b<<<1, 64, 0, stream>>>(partials, nch);
    k_scan_c<<<nch, 1024, 0, stream>>>(row_off, partials, N, E);
    k_fill<<<(E + 255) / 256, 256, 0, stream>>>(head, tail, etype, E, row_off, cursor,
                                                c_head, c_tail, c_type);
    k_blk<<<(N + 255) / 256, 256, 0, stream>>>(row_off, N, blk_n0, blk_n1);
    k_meta<<<(NB + 255) / 256, 256, 0, stream>>>(blk_n0, blk_n1, row_off, NB, meta);

    // hop 0: seed -> aggbA ; hop 1: aggbA -> aggbB ; hop 2: aggbB -> out (w/ a1=aggbA, a2=aggbB)
    k_qproj<<<(N + 127) / 128, 256, 0, stream>>>(aggb0, (const uint4*)qwT_swz, qh, N);
    k_fused<<<NB, 256, 0, stream>>>(aggb0, eembb, kwT, qh, c_head, c_tail, c_type,
                                    row_off, meta, entity, aggbA, aggbB,
                                    aggbA, (float*)d_out, 0, E);
    k_qproj<<<(N + 127) / 128, 256, 0, stream>>>(aggbA, (const uint4*)qwT_swz, qh, N);
    k_fused<<<NB, 256, 0, stream>>>(aggbA, eembb, kwT, qh, c_head, c_tail, c_type,
                                    row_off, meta, entity, aggbA, aggbB,
                                    aggbB, (float*)d_out, 1, E);
    k_qproj<<<(N + 127) / 128, 256, 0, stream>>>(aggbB, (const uint4*)qwT_swz, qh, N);
    k_fused<<<NB, 256, 0, stream>>>(aggbB, eembb, kwT, qh, c_head, c_tail, c_type,
                                    row_off, meta, entity, aggbA, aggbB,
                                    aggb0 /*unused*/, (float*)d_out, 2, E);
}